// Round 9
// baseline (170.778 us; speedup 1.0000x reference)
//
#include <hip/hip_runtime.h>
#include <hip/hip_bf16.h>

#define N_SRC   131072
#define N_DST   65536
#define N_EDGES 524288
#define D       128      // D_IN == D_OUT == 128

typedef __bf16 bf16x8 __attribute__((ext_vector_type(8)));
typedef float  f32x4  __attribute__((ext_vector_type(4)));
typedef float  fvec4  __attribute__((ext_vector_type(4)));  // for NT builtins

#define CONV_BLOCKS 8192   // (N_SRC*D) / (256 threads * 8 elems) = 8192
#define W_BLOCKS    64     // 64*256 = 16384 = D*D elements

// ---------------------------------------------------------------------------
// Kernel 1 (fused prep): role-split grid.
//  blocks [0, CONV_BLOCKS)                : feat fp32 -> bf16 (streaming)
//  blocks [CONV_BLOCKS, CONV+n_bnd)       : sorted dst -> CSR row_start
//  blocks [CONV+n_bnd, CONV+n_bnd+64)     : W fp32 [k][n] -> Wt bf16 [n][k]
// fp32 feat loads are nontemporal: dead after conversion — keep L3 for
// feat_bf, which the gather re-reads (R4/R7 A/B: gather is HBM-fetch-bound;
// L3 retention of feat_bf is the only remaining lever).
// ---------------------------------------------------------------------------
__global__ __launch_bounds__(256) void prep_kernel(
    const float* __restrict__ feat,
    const int*   __restrict__ dst, int n_edges, int n_bnd_blocks,
    const float* __restrict__ W_self, const float* __restrict__ W_neigh,
    __bf16* __restrict__ feat_bf,
    int*    __restrict__ row_start,
    __bf16* __restrict__ Wt_self, __bf16* __restrict__ Wt_neigh)
{
    const int b = blockIdx.x;
    const int t = threadIdx.x;

    if (b < CONV_BLOCKS) {
        const size_t i0 = ((size_t)b * 256 + t) * 8;
        const fvec4 a0 = __builtin_nontemporal_load((const fvec4*)&feat[i0]);
        const fvec4 a1 = __builtin_nontemporal_load((const fvec4*)&feat[i0 + 4]);
        bf16x8 o;
        o[0] = (__bf16)a0[0]; o[1] = (__bf16)a0[1]; o[2] = (__bf16)a0[2]; o[3] = (__bf16)a0[3];
        o[4] = (__bf16)a1[0]; o[5] = (__bf16)a1[1]; o[6] = (__bf16)a1[2]; o[7] = (__bf16)a1[3];
        *(bf16x8*)&feat_bf[i0] = o;   // cacheable: gather working set
    } else if (b < CONV_BLOCKS + n_bnd_blocks) {
        const int e = (b - CONV_BLOCKS) * 256 + t;
        if (e < n_edges) {
            const int d    = dst[e];
            const int prev = (e == 0) ? -1 : dst[e - 1];
            for (int r = prev + 1; r <= d; ++r) row_start[r] = e;
            if (e == n_edges - 1)
                for (int r = d + 1; r <= N_DST; ++r) row_start[r] = n_edges;
        }
    } else {
        const int wb  = b - CONV_BLOCKS - n_bnd_blocks;  // 0..63
        const int idx = wb * 256 + t;                    // 0..16383
        const int k = idx >> 7, n = idx & 127;
        Wt_self [n * D + k] = (__bf16)W_self [k * D + n];
        Wt_neigh[n * D + k] = (__bf16)W_neigh[k * D + n];
    }
}

// ---------------------------------------------------------------------------
// Kernel 2: neighbor mean over bf16 feat. 16-lane group per dst row; lane
// covers 8 cols (16 B) -> each edge = one coalesced 256 B segment.
// Predicated unroll-8: 8 independent loads always in flight, no serial
// remainder. h_neigh store is nontemporal (streaming; would evict feat_bf).
// ---------------------------------------------------------------------------
__global__ __launch_bounds__(256) void neigh_kernel(
    const __bf16* __restrict__ feat_bf,
    const int*    __restrict__ src,
    const int*    __restrict__ row_start,
    __bf16*       __restrict__ h_neigh)
{
    const int g    = threadIdx.x >> 4;        // group 0..15
    const int lane = threadIdx.x & 15;
    const int row  = blockIdx.x * 16 + g;
    const int s0   = row_start[row];
    const int s1   = row_start[row + 1];
    const int co   = lane * 8;

    float acc[8] = {0.f, 0.f, 0.f, 0.f, 0.f, 0.f, 0.f, 0.f};

    for (int base = s0; base < s1; base += 8) {
        int idx[8];
        #pragma unroll
        for (int j = 0; j < 8; ++j) {
            const int e = base + j;
            idx[j] = src[e < s1 ? e : s1 - 1];
        }
        bf16x8 v[8];
        #pragma unroll
        for (int j = 0; j < 8; ++j)
            v[j] = *(const bf16x8*)&feat_bf[(size_t)idx[j] * D + co];
        #pragma unroll
        for (int j = 0; j < 8; ++j) {
            const float m = (base + j < s1) ? 1.0f : 0.0f;
            #pragma unroll
            for (int c = 0; c < 8; ++c)
                acc[c] = fmaf(m, (float)v[j][c], acc[c]);
        }
    }

    const float inv = 1.0f / fmaxf((float)(s1 - s0), 1.0f);
    bf16x8 o;
    #pragma unroll
    for (int c = 0; c < 8; ++c) o[c] = (__bf16)(acc[c] * inv);
    __builtin_nontemporal_store(o, (bf16x8*)&h_neigh[(size_t)row * D + co]);
}

// ---------------------------------------------------------------------------
// Kernel 3: out = feat_bf[:N_DST] @ W_self + h_neigh @ W_neigh + biases.
// MFMA bf16 16x16x32, fp32 accumulate. No LDS, no barriers.
// Fragment layouts (HW-verified rounds 1-7):
//   A: lane holds A[m = lane&15][k = (lane>>4)*8 + j]
//   B: lane holds B[k = (lane>>4)*8 + j][n = lane&15]   (from Wt[n][k])
//   C/D: col = lane&15, row = (lane>>4)*4 + reg
// out stores nontemporal (pure streaming output).
// ---------------------------------------------------------------------------
#define MREP 2

__global__ __launch_bounds__(256) void gemm_kernel(
    const __bf16* __restrict__ feat_bf,   // bf16, first N_DST rows used
    const __bf16* __restrict__ h_neigh,   // bf16 N_DST x D
    const __bf16* __restrict__ Wt_self,   // bf16 [n][k]
    const __bf16* __restrict__ Wt_neigh,  // bf16 [n][k]
    const float*  __restrict__ b_self,
    const float*  __restrict__ b_neigh,
    float*        __restrict__ out)
{
    const int t    = threadIdx.x;
    const int w    = t >> 6;          // wave 0..3
    const int l    = t & 63;
    const int m16  = l & 15;
    const int quad = l >> 4;          // 0..3
    const int kb   = quad * 8;
    const int rowbase = blockIdx.x * (64 * MREP) + w * (16 * MREP);

    f32x4 acc[MREP][8];
    #pragma unroll
    for (int rp = 0; rp < MREP; ++rp)
        #pragma unroll
        for (int nb = 0; nb < 8; ++nb)
            acc[rp][nb] = (f32x4){0.f, 0.f, 0.f, 0.f};

    const __bf16* __restrict__ Aptr[2] = {feat_bf, h_neigh};
    const __bf16* __restrict__ Wptr[2] = {Wt_self, Wt_neigh};

    #pragma unroll
    for (int p = 0; p < 2; ++p) {
        const __bf16* __restrict__ A = Aptr[p];
        const __bf16* __restrict__ W = Wptr[p];
        #pragma unroll
        for (int ks = 0; ks < 4; ++ks) {
            bf16x8 afrag[MREP];
            #pragma unroll
            for (int rp = 0; rp < MREP; ++rp)
                afrag[rp] = *(const bf16x8*)&A[(size_t)(rowbase + rp * 16 + m16) * D + ks * 32 + kb];
            #pragma unroll
            for (int nb = 0; nb < 8; ++nb) {
                const bf16x8 bfrag = *(const bf16x8*)&W[(size_t)(nb * 16 + m16) * D + ks * 32 + kb];
                #pragma unroll
                for (int rp = 0; rp < MREP; ++rp)
                    acc[rp][nb] = __builtin_amdgcn_mfma_f32_16x16x32_bf16(
                        afrag[rp], bfrag, acc[rp][nb], 0, 0, 0);
            }
        }
    }

    // epilogue
    #pragma unroll
    for (int nb = 0; nb < 8; ++nb) {
        const int col  = nb * 16 + m16;
        const float bias = b_self[col] + b_neigh[col];
        #pragma unroll
        for (int rp = 0; rp < MREP; ++rp) {
            const int orow0 = rowbase + rp * 16 + quad * 4;
            #pragma unroll
            for (int r = 0; r < 4; ++r)
                __builtin_nontemporal_store(acc[rp][nb][r] + bias,
                    &out[(size_t)(orow0 + r) * D + col]);
        }
    }
}

// ---------------------------------------------------------------------------
extern "C" void kernel_launch(void* const* d_in, const int* in_sizes, int n_in,
                              void* d_out, int out_size, void* d_ws, size_t ws_size,
                              hipStream_t stream)
{
    const float* feat    = (const float*)d_in[0];
    const float* W_self  = (const float*)d_in[1];
    const float* b_self  = (const float*)d_in[2];
    const float* W_neigh = (const float*)d_in[3];
    const float* b_neigh = (const float*)d_in[4];
    const int*   src_idx = (const int*)d_in[5];
    const int*   dst_idx = (const int*)d_in[6];
    const int n_edges = in_sizes[5];

    // workspace layout
    char* ws = (char*)d_ws;
    __bf16* feat_bf   = (__bf16*)ws;                                 // 32 MB
    __bf16* h_neigh   = feat_bf + (size_t)N_SRC * D;                 // 16 MB
    int*    row_start = (int*)(h_neigh + (size_t)N_DST * D);         // 256 KB
    __bf16* Wt_self   = (__bf16*)(row_start + N_DST + 16);
    __bf16* Wt_neigh  = Wt_self + D * D;

    const int n_bnd = (n_edges + 255) / 256;
    prep_kernel<<<CONV_BLOCKS + n_bnd + W_BLOCKS, 256, 0, stream>>>(
        feat, dst_idx, n_edges, n_bnd, W_self, W_neigh,
        feat_bf, row_start, Wt_self, Wt_neigh);

    neigh_kernel<<<N_DST / 16, 256, 0, stream>>>(feat_bf, src_idx, row_start, h_neigh);

    gemm_kernel<<<N_DST / (64 * MREP), 256, 0, stream>>>(
        feat_bf, h_neigh, Wt_self, Wt_neigh, b_self, b_neigh, (float*)d_out);
}